// Round 1
// baseline (881.836 us; speedup 1.0000x reference)
//
#include <hip/hip_runtime.h>
#include <math.h>

#define U_DIM 256
#define NK_DIM 128
#define B_DIM 4096

// ---------------- Kernel A: fold weights ----------------
// grid 256, block 256
// M1s[l*256+j]      = (1/16) * sum_i Wq[i*256+l] * Wk[i*256+j]
// c1s[j]            = (1/16) * sum_i bq[i] * Wk[i*256+j]
// Bd[j*256+l]       = sum_i Wf[l*512+i] * Wv[i*256+j]      (= (Wf1*Wv)^T)
// Bd[(256+i)*256+l] = Wf[l*512+256+i]                      (= Wf2^T)
// c2[l]             = sum_i Wf[l*512+i]*bv[i] + bf[l]
__global__ void precompute_kernel(const float* __restrict__ Wq,
                                  const float* __restrict__ bq,
                                  const float* __restrict__ Wk,
                                  const float* __restrict__ Wv,
                                  const float* __restrict__ bv,
                                  const float* __restrict__ Wf,
                                  const float* __restrict__ bf,
                                  float* __restrict__ M1s,
                                  float* __restrict__ c1s,
                                  float* __restrict__ Bd,
                                  float* __restrict__ c2) {
    __shared__ float wqcol[256];
    __shared__ float wfrow[256];
    __shared__ float red[256];
    int l = blockIdx.x, t = threadIdx.x;
    wqcol[t] = Wq[t * 256 + l];
    wfrow[t] = Wf[l * 512 + t];
    __syncthreads();
    float m1 = 0.f, m2 = 0.f;
    for (int i = 0; i < 256; ++i) {
        float wk = Wk[i * 256 + t];
        float wv = Wv[i * 256 + t];
        m1 += wqcol[i] * wk;
        m2 += wfrow[i] * wv;
    }
    M1s[l * 256 + t] = m1 * 0.0625f;
    Bd[t * 256 + l] = m2;
    Bd[(256 + t) * 256 + l] = Wf[l * 512 + 256 + t];
    red[t] = wfrow[t] * bv[t];
    __syncthreads();
    for (int s = 128; s > 0; s >>= 1) {
        if (t < s) red[t] += red[t + s];
        __syncthreads();
    }
    if (t == 0) c2[l] = red[0] + bf[l];
    if (l == 0) {
        float c1 = 0.f;
        for (int i = 0; i < 256; ++i) c1 += bq[i] * Wk[i * 256 + t];
        c1s[t] = c1 * 0.0625f;
    }
}

// ---------------- Kernel B: qk = query @ M1s + c1s ----------------
// grid 512 (8 rows/block), block 256
__global__ void qk_kernel(const float* __restrict__ query,
                          const float* __restrict__ M1s,
                          const float* __restrict__ c1s,
                          float* __restrict__ qk) {
    __shared__ __align__(16) float qs[8][256];
    int t = threadIdx.x;
    int b0 = blockIdx.x * 8;
    #pragma unroll
    for (int r = 0; r < 8; ++r) qs[r][t] = query[(size_t)(b0 + r) * 256 + t];
    __syncthreads();
    float acc[8] = {0.f, 0.f, 0.f, 0.f, 0.f, 0.f, 0.f, 0.f};
    #pragma unroll 2
    for (int k0 = 0; k0 < 256; k0 += 4) {
        float b0v = M1s[(k0 + 0) * 256 + t];
        float b1v = M1s[(k0 + 1) * 256 + t];
        float b2v = M1s[(k0 + 2) * 256 + t];
        float b3v = M1s[(k0 + 3) * 256 + t];
        #pragma unroll
        for (int r = 0; r < 8; ++r) {
            float4 a = *(const float4*)&qs[r][k0];
            acc[r] += a.x * b0v + a.y * b1v + a.z * b2v + a.w * b3v;
        }
    }
    float c1 = c1s[t];
    #pragma unroll
    for (int r = 0; r < 8; ++r) qk[(size_t)(b0 + r) * 256 + t] = acc[r] + c1;
}

// ---------------- Kernel C: online-softmax attention over raw keys ----------------
// grid 4096 (one b per block), block 256 (4 waves)
// kctx[b,u] = sum_n softmax_n(qk[b]·keys[b,n]) * keys[b,n,u]
// Each key row is loaded from HBM exactly once (kept in registers between
// score computation and weighted accumulation).
__global__ __launch_bounds__(256) void attn_kernel(const float* __restrict__ keys,
                                                   const float* __restrict__ qk,
                                                   float* __restrict__ kctx) {
    int b = blockIdx.x;
    int t = threadIdx.x;
    int lane = t & 63;
    int w = t >> 6;
    const float4* K4 = (const float4*)keys + (size_t)b * (NK_DIM * U_DIM / 4);
    float4 q4 = ((const float4*)qk)[(size_t)b * 64 + lane];
    __shared__ float s_sc[32];
    __shared__ float s_L[4];
    __shared__ __align__(16) float4 s_acc[4][64];
    float m = -INFINITY, L = 0.f;
    float4 acc = {0.f, 0.f, 0.f, 0.f};
    for (int c = 0; c < 4; ++c) {
        int n0 = c * 32 + w * 8;
        float4 kv[8];
        #pragma unroll
        for (int r = 0; r < 8; ++r) kv[r] = K4[(n0 + r) * 64 + lane];
        #pragma unroll
        for (int r = 0; r < 8; ++r) {
            float s = kv[r].x * q4.x + kv[r].y * q4.y + kv[r].z * q4.z + kv[r].w * q4.w;
            #pragma unroll
            for (int msk = 32; msk > 0; msk >>= 1) s += __shfl_xor(s, msk, 64);
            if (lane == r) s_sc[w * 8 + r] = s;
        }
        __syncthreads();
        float cmax = -INFINITY;
        #pragma unroll
        for (int i = 0; i < 32; ++i) cmax = fmaxf(cmax, s_sc[i]);
        float nm = fmaxf(m, cmax);
        float scale = __expf(m - nm);
        m = nm;
        L *= scale;
        acc.x *= scale; acc.y *= scale; acc.z *= scale; acc.w *= scale;
        #pragma unroll
        for (int r = 0; r < 8; ++r) {
            float p = __expf(s_sc[w * 8 + r] - nm);
            L += p;
            acc.x += p * kv[r].x; acc.y += p * kv[r].y;
            acc.z += p * kv[r].z; acc.w += p * kv[r].w;
        }
        __syncthreads();
    }
    s_acc[w][lane] = acc;
    if (lane == 0) s_L[w] = L;
    __syncthreads();
    if (w == 0) {
        float4 a0 = s_acc[0][lane], a1 = s_acc[1][lane];
        float4 a2 = s_acc[2][lane], a3 = s_acc[3][lane];
        float inv = 1.f / (s_L[0] + s_L[1] + s_L[2] + s_L[3]);
        float4 o;
        o.x = (a0.x + a1.x + a2.x + a3.x) * inv;
        o.y = (a0.y + a1.y + a2.y + a3.y) * inv;
        o.z = (a0.z + a1.z + a2.z + a3.z) * inv;
        o.w = (a0.w + a1.w + a2.w + a3.w) * inv;
        ((float4*)kctx)[(size_t)b * 64 + lane] = o;
    }
}

// ---------------- Kernel D: out = relu([kctx|query] @ Bd + c2) ----------------
// grid 512 (8 rows/block), block 256
__global__ void out_kernel(const float* __restrict__ kctx,
                           const float* __restrict__ query,
                           const float* __restrict__ Bd,
                           const float* __restrict__ c2,
                           float* __restrict__ out) {
    __shared__ __align__(16) float as[8][512];
    int t = threadIdx.x;
    int b0 = blockIdx.x * 8;
    #pragma unroll
    for (int r = 0; r < 8; ++r) {
        as[r][t] = kctx[(size_t)(b0 + r) * 256 + t];
        as[r][256 + t] = query[(size_t)(b0 + r) * 256 + t];
    }
    __syncthreads();
    float acc[8] = {0.f, 0.f, 0.f, 0.f, 0.f, 0.f, 0.f, 0.f};
    #pragma unroll 2
    for (int k0 = 0; k0 < 512; k0 += 4) {
        float b0v = Bd[(k0 + 0) * 256 + t];
        float b1v = Bd[(k0 + 1) * 256 + t];
        float b2v = Bd[(k0 + 2) * 256 + t];
        float b3v = Bd[(k0 + 3) * 256 + t];
        #pragma unroll
        for (int r = 0; r < 8; ++r) {
            float4 a = *(const float4*)&as[r][k0];
            acc[r] += a.x * b0v + a.y * b1v + a.z * b2v + a.w * b3v;
        }
    }
    float c = c2[t];
    #pragma unroll
    for (int r = 0; r < 8; ++r)
        out[(size_t)(b0 + r) * 256 + t] = fmaxf(acc[r] + c, 0.f);
}

extern "C" void kernel_launch(void* const* d_in, const int* in_sizes, int n_in,
                              void* d_out, int out_size, void* d_ws, size_t ws_size,
                              hipStream_t stream) {
    const float* query = (const float*)d_in[0];
    const float* keys  = (const float*)d_in[1];
    const float* Wq    = (const float*)d_in[2];
    const float* bq    = (const float*)d_in[3];
    const float* Wk    = (const float*)d_in[4];
    // d_in[5] = bk: dropped (softmax shift-invariance)
    const float* Wv    = (const float*)d_in[6];
    const float* bv    = (const float*)d_in[7];
    const float* Wf    = (const float*)d_in[8];
    const float* bf    = (const float*)d_in[9];
    float* out = (float*)d_out;

    float* ws   = (float*)d_ws;
    float* M1s  = ws;                      // 65536
    float* c1s  = M1s + 65536;             // 256
    float* Bd   = c1s + 256;               // 131072
    float* c2   = Bd + 131072;             // 256
    float* qk   = c2 + 256;                // 4096*256
    float* kctx = qk + 4096 * 256;         // 4096*256
    // total: 2,294,272 floats = ~9.2 MB of workspace

    hipLaunchKernelGGL(precompute_kernel, dim3(256), dim3(256), 0, stream,
                       Wq, bq, Wk, Wv, bv, Wf, bf, M1s, c1s, Bd, c2);
    hipLaunchKernelGGL(qk_kernel, dim3(512), dim3(256), 0, stream,
                       query, M1s, c1s, qk);
    hipLaunchKernelGGL(attn_kernel, dim3(4096), dim3(256), 0, stream,
                       keys, qk, kctx);
    hipLaunchKernelGGL(out_kernel, dim3(512), dim3(256), 0, stream,
                       kctx, query, Bd, c2, out);
}

// Round 7
// 816.054 us; speedup vs baseline: 1.0806x; 1.0806x over previous
//
#include <hip/hip_runtime.h>
#include <math.h>

#define U_DIM 256
#define NK_DIM 128
#define B_DIM 4096

// native clang vector type — __builtin_nontemporal_load rejects HIP_vector_type
typedef float nvf4 __attribute__((ext_vector_type(4)));

// ---------------- Kernel A: fold weights ----------------
// grid 256, block 256
// M1s[l*256+j]      = (1/16) * sum_i Wq[i*256+l] * Wk[i*256+j]
// c1s[j]            = (1/16) * sum_i bq[i] * Wk[i*256+j]
// Bd[j*256+l]       = sum_i Wf[l*512+i] * Wv[i*256+j]      (= (Wf1*Wv)^T)
// Bd[(256+i)*256+l] = Wf[l*512+256+i]                      (= Wf2^T)
// c2[l]             = sum_i Wf[l*512+i]*bv[i] + bf[l]
__global__ void precompute_kernel(const float* __restrict__ Wq,
                                  const float* __restrict__ bq,
                                  const float* __restrict__ Wk,
                                  const float* __restrict__ Wv,
                                  const float* __restrict__ bv,
                                  const float* __restrict__ Wf,
                                  const float* __restrict__ bf,
                                  float* __restrict__ M1s,
                                  float* __restrict__ c1s,
                                  float* __restrict__ Bd,
                                  float* __restrict__ c2) {
    __shared__ float wqcol[256];
    __shared__ float wfrow[256];
    __shared__ float red[256];
    int l = blockIdx.x, t = threadIdx.x;
    wqcol[t] = Wq[t * 256 + l];
    wfrow[t] = Wf[l * 512 + t];
    __syncthreads();
    float m1 = 0.f, m2 = 0.f;
    for (int i = 0; i < 256; ++i) {
        float wk = Wk[i * 256 + t];
        float wv = Wv[i * 256 + t];
        m1 += wqcol[i] * wk;
        m2 += wfrow[i] * wv;
    }
    M1s[l * 256 + t] = m1 * 0.0625f;
    Bd[t * 256 + l] = m2;
    Bd[(256 + t) * 256 + l] = Wf[l * 512 + 256 + t];
    red[t] = wfrow[t] * bv[t];
    __syncthreads();
    for (int s = 128; s > 0; s >>= 1) {
        if (t < s) red[t] += red[t + s];
        __syncthreads();
    }
    if (t == 0) c2[l] = red[0] + bf[l];
    if (l == 0) {
        float c1 = 0.f;
        for (int i = 0; i < 256; ++i) c1 += bq[i] * Wk[i * 256 + t];
        c1s[t] = c1 * 0.0625f;
    }
}

// ---------------- Kernel B: qk = query @ M1s + c1s ----------------
// grid 512 (8 rows/block), block 256
__global__ void qk_kernel(const float* __restrict__ query,
                          const float* __restrict__ M1s,
                          const float* __restrict__ c1s,
                          float* __restrict__ qk) {
    __shared__ __align__(16) float qs[8][256];
    int t = threadIdx.x;
    int b0 = blockIdx.x * 8;
    #pragma unroll
    for (int r = 0; r < 8; ++r) qs[r][t] = query[(size_t)(b0 + r) * 256 + t];
    __syncthreads();
    float acc[8] = {0.f, 0.f, 0.f, 0.f, 0.f, 0.f, 0.f, 0.f};
    #pragma unroll 2
    for (int k0 = 0; k0 < 256; k0 += 4) {
        float b0v = M1s[(k0 + 0) * 256 + t];
        float b1v = M1s[(k0 + 1) * 256 + t];
        float b2v = M1s[(k0 + 2) * 256 + t];
        float b3v = M1s[(k0 + 3) * 256 + t];
        #pragma unroll
        for (int r = 0; r < 8; ++r) {
            float4 a = *(const float4*)&qs[r][k0];
            acc[r] += a.x * b0v + a.y * b1v + a.z * b2v + a.w * b3v;
        }
    }
    float c1 = c1s[t];
    #pragma unroll
    for (int r = 0; r < 8; ++r) qk[(size_t)(b0 + r) * 256 + t] = acc[r] + c1;
}

// ---------------- Kernel C: barrier-free online-softmax attention ----------------
// grid 4096 (one b per block), block 256 (4 waves).
// Wave w privately owns keys rows [w*32, w*32+32) and maintains its own
// running (m, L, acc) online softmax — the 6-level __shfl_xor butterfly
// broadcasts each score to all 64 lanes, so NO LDS and NO barriers in the
// main loop (barriers force a vmcnt(0) drain that idles HBM). A single
// __syncthreads merges the 4 wave-partials at the end.
// Each key row is read from HBM exactly once, nontemporal (stream, no reuse).
__global__ __launch_bounds__(256) void attn_kernel(const float* __restrict__ keys,
                                                   const float* __restrict__ qk,
                                                   float* __restrict__ kctx) {
    int b = blockIdx.x;
    int t = threadIdx.x;
    int lane = t & 63;
    int w = t >> 6;
    const nvf4* K4 = (const nvf4*)keys + (size_t)b * (NK_DIM * U_DIM / 4)
                     + (size_t)(w * 32) * 64 + lane;
    float4 q4 = ((const float4*)qk)[(size_t)b * 64 + lane];
    float m = -INFINITY, L = 0.f;
    float4 acc = {0.f, 0.f, 0.f, 0.f};

    nvf4 ka[8], kb[8];

    auto load8 = [&](nvf4* kv, int base) {
        #pragma unroll
        for (int r = 0; r < 8; ++r)
            kv[r] = __builtin_nontemporal_load(K4 + (base + r) * 64);
    };
    auto proc8 = [&](const nvf4* kv) {
        float s[8];
        #pragma unroll
        for (int r = 0; r < 8; ++r) {
            float d = kv[r].x * q4.x + kv[r].y * q4.y + kv[r].z * q4.z + kv[r].w * q4.w;
            #pragma unroll
            for (int msk = 32; msk > 0; msk >>= 1) d += __shfl_xor(d, msk, 64);
            s[r] = d;  // full 256-dim dot, uniform across lanes
        }
        float cmax = fmaxf(fmaxf(fmaxf(s[0], s[1]), fmaxf(s[2], s[3])),
                           fmaxf(fmaxf(s[4], s[5]), fmaxf(s[6], s[7])));
        float nm = fmaxf(m, cmax);
        float sc = __expf(m - nm);
        m = nm;
        L *= sc;
        acc.x *= sc; acc.y *= sc; acc.z *= sc; acc.w *= sc;
        #pragma unroll
        for (int r = 0; r < 8; ++r) {
            float p = __expf(s[r] - nm);
            L += p;
            acc.x += p * kv[r].x; acc.y += p * kv[r].y;
            acc.z += p * kv[r].z; acc.w += p * kv[r].w;
        }
    };

    // software-pipelined: loads of chunk c+1 issued before compute of chunk c
    load8(ka, 0);
    load8(kb, 8);  proc8(ka);
    load8(ka, 16); proc8(kb);
    load8(kb, 24); proc8(ka);
    proc8(kb);

    // merge 4 wave-partials
    __shared__ __align__(16) float4 s_acc[4][64];
    __shared__ float s_m[4];
    __shared__ float s_L[4];
    s_acc[w][lane] = acc;
    if (lane == 0) { s_m[w] = m; s_L[w] = L; }
    __syncthreads();
    if (w == 0) {
        float m0 = s_m[0], m1 = s_m[1], m2 = s_m[2], m3 = s_m[3];
        float ms = fmaxf(fmaxf(m0, m1), fmaxf(m2, m3));
        float w0 = __expf(m0 - ms), w1 = __expf(m1 - ms);
        float w2 = __expf(m2 - ms), w3 = __expf(m3 - ms);
        float inv = 1.f / (s_L[0] * w0 + s_L[1] * w1 + s_L[2] * w2 + s_L[3] * w3);
        float4 a0 = s_acc[0][lane], a1 = s_acc[1][lane];
        float4 a2 = s_acc[2][lane], a3 = s_acc[3][lane];
        float4 o;
        o.x = (a0.x * w0 + a1.x * w1 + a2.x * w2 + a3.x * w3) * inv;
        o.y = (a0.y * w0 + a1.y * w1 + a2.y * w2 + a3.y * w3) * inv;
        o.z = (a0.z * w0 + a1.z * w1 + a2.z * w2 + a3.z * w3) * inv;
        o.w = (a0.w * w0 + a1.w * w1 + a2.w * w2 + a3.w * w3) * inv;
        ((float4*)kctx)[(size_t)b * 64 + lane] = o;
    }
}

// ---------------- Kernel D: out = relu([kctx|query] @ Bd + c2) ----------------
// grid 512 (8 rows/block), block 256
__global__ void out_kernel(const float* __restrict__ kctx,
                           const float* __restrict__ query,
                           const float* __restrict__ Bd,
                           const float* __restrict__ c2,
                           float* __restrict__ out) {
    __shared__ __align__(16) float as[8][512];
    int t = threadIdx.x;
    int b0 = blockIdx.x * 8;
    #pragma unroll
    for (int r = 0; r < 8; ++r) {
        as[r][t] = kctx[(size_t)(b0 + r) * 256 + t];
        as[r][256 + t] = query[(size_t)(b0 + r) * 256 + t];
    }
    __syncthreads();
    float acc[8] = {0.f, 0.f, 0.f, 0.f, 0.f, 0.f, 0.f, 0.f};
    #pragma unroll 2
    for (int k0 = 0; k0 < 512; k0 += 4) {
        float b0v = Bd[(k0 + 0) * 256 + t];
        float b1v = Bd[(k0 + 1) * 256 + t];
        float b2v = Bd[(k0 + 2) * 256 + t];
        float b3v = Bd[(k0 + 3) * 256 + t];
        #pragma unroll
        for (int r = 0; r < 8; ++r) {
            float4 a = *(const float4*)&as[r][k0];
            acc[r] += a.x * b0v + a.y * b1v + a.z * b2v + a.w * b3v;
        }
    }
    float c = c2[t];
    #pragma unroll
    for (int r = 0; r < 8; ++r)
        out[(size_t)(b0 + r) * 256 + t] = fmaxf(acc[r] + c, 0.f);
}

extern "C" void kernel_launch(void* const* d_in, const int* in_sizes, int n_in,
                              void* d_out, int out_size, void* d_ws, size_t ws_size,
                              hipStream_t stream) {
    const float* query = (const float*)d_in[0];
    const float* keys  = (const float*)d_in[1];
    const float* Wq    = (const float*)d_in[2];
    const float* bq    = (const float*)d_in[3];
    const float* Wk    = (const float*)d_in[4];
    // d_in[5] = bk: dropped (softmax shift-invariance)
    const float* Wv    = (const float*)d_in[6];
    const float* bv    = (const float*)d_in[7];
    const float* Wf    = (const float*)d_in[8];
    const float* bf    = (const float*)d_in[9];
    float* out = (float*)d_out;

    float* ws   = (float*)d_ws;
    float* M1s  = ws;                      // 65536
    float* c1s  = M1s + 65536;             // 256
    float* Bd   = c1s + 256;               // 131072
    float* c2   = Bd + 131072;             // 256
    float* qk   = c2 + 256;                // 4096*256
    float* kctx = qk + 4096 * 256;         // 4096*256
    // total: ~9.2 MB of workspace

    hipLaunchKernelGGL(precompute_kernel, dim3(256), dim3(256), 0, stream,
                       Wq, bq, Wk, Wv, bv, Wf, bf, M1s, c1s, Bd, c2);
    hipLaunchKernelGGL(qk_kernel, dim3(512), dim3(256), 0, stream,
                       query, M1s, c1s, qk);
    hipLaunchKernelGGL(attn_kernel, dim3(4096), dim3(256), 0, stream,
                       keys, qk, kctx);
    hipLaunchKernelGGL(out_kernel, dim3(512), dim3(256), 0, stream,
                       kctx, query, Bd, c2, out);
}